// Round 8
// baseline (887.330 us; speedup 1.0000x reference)
//
#include <hip/hip_runtime.h>

#define DIMS 64
#define SCAN_CHUNK 2048  // 256 threads * 8 elems
#define BSHIFT 10        // 1024 rows per bucket
#define BROWS (1 << BSHIFT)
#define NB_MAX 304       // >= ceil(300K/1024)=293
#define BCAP 65536       // fixed bucket capacity (mean ~34K + drain pads <54K)
#define SCAP 40          // staged entries per bucket (mirror staging doubles arrival)
#define SPITCH 41        // odd pitch -> bank-conflict-free across buckets
#define PA_THREADS 256
#define PA_K 4           // edge-PAIRS per thread per round (int4 vector loads)
#define PA_ROUND (PA_THREADS * PA_K)  // 1024 pairs -> 2048 staged entries/round
#define PA_CHUNK 4096    // edge-pairs per block (4 rounds)
#define PB_THREADS 512
#define SENTINEL 0xFFFFFFFFu
// fp8 e4m3 storage scale: S-values ~2e-3 sit below e4m3 min-normal 2^-6;
// x1024 centers them near 1.0 (full mantissa precision). The scale
// self-propagates through spmm (out = rs2 * sum(in)) and is divided out
// only at the fp32 batch-gather epilogues.
#define FP8_SCALE 1024.0f
#define FP8_INV (1.0f / 1024.0f)

typedef float v2f __attribute__((ext_vector_type(2)));

// nt 4B load (edge col stream): keep the 40MB/layer CSR stream from
// polluting L2, which stays dedicated to the hot 19MB fp8 gather target
__device__ __forceinline__ int ld_nt_int(const int* p) {
  return __builtin_nontemporal_load(p);
}

// decode 4 fp8 (one dword) and accumulate into acc[base..base+3]
#define ACC_DW(w, base)                                            \
  {                                                                \
    v2f l_ = __builtin_amdgcn_cvt_pk_f32_fp8((int)(w), false);     \
    v2f h_ = __builtin_amdgcn_cvt_pk_f32_fp8((int)(w), true);      \
    acc[(base) + 0] += l_[0];                                      \
    acc[(base) + 1] += l_[1];                                      \
    acc[(base) + 2] += h_[0];                                      \
    acc[(base) + 3] += h_[1];                                      \
  }

// ---------------------------------------------------------------------------
// Es0 = FP8_SCALE * rs * concat(U,V) stored fp8 e4m3 (pre-scaled S-space)
// ---------------------------------------------------------------------------
__global__ __launch_bounds__(256) void init_es_kernel(
    const float* __restrict__ U, const float* __restrict__ V,
    const float* __restrict__ rs, unsigned* __restrict__ Es32,
    int nU_elems, int total_elems) {
  int t = blockIdx.x * blockDim.x + threadIdx.x;
  int i4 = t * 4;
  if (i4 >= total_elems) return;
  float4 v = (i4 < nU_elems)
      ? *reinterpret_cast<const float4*>(U + i4)
      : *reinterpret_cast<const float4*>(V + (i4 - nU_elems));
  float s = rs[i4 >> 6] * FP8_SCALE;
  int w = 0;
  w = __builtin_amdgcn_cvt_pk_fp8_f32(v.x * s, v.y * s, w, false);
  w = __builtin_amdgcn_cvt_pk_fp8_f32(v.z * s, v.w * s, w, true);
  Es32[t] = (unsigned)w;
}

// ---------------------------------------------------------------------------
// Pass A: LDS-staged multisplit of packed (row_low<<19 | col) 4B entries into
// fixed-capacity row-range buckets (base = b*BCAP).
// Mirror staging: the symmetric COO's second half is exactly the mirror of
// the first, so each thread loads first-half (u,i) pairs and stages BOTH
// orientations -- same staged multiset, half the rounds.
// ---------------------------------------------------------------------------
__global__ __launch_bounds__(PA_THREADS) void pass_a_kernel(
    const int* __restrict__ rows, const int* __restrict__ cols,
    unsigned* __restrict__ temp, int* __restrict__ gcur, int nnz, int nb) {
  __shared__ unsigned stage[NB_MAX * SPITCH];
  __shared__ int scnt[NB_MAX];
  for (int b = threadIdx.x; b < nb; b += PA_THREADS) scnt[b] = 0;
  __syncthreads();

  const int half = nnz >> 1;
  const int c0 = blockIdx.x * PA_CHUNK;
  const int c1 = min(half, c0 + PA_CHUNK);

  for (int rd = 0; rd < PA_CHUNK / PA_ROUND; ++rd) {
    int base = c0 + rd * PA_ROUND + threadIdx.x * PA_K;

    unsigned packed[2 * PA_K];
    int bkt[2 * PA_K];
    unsigned pend = 0;  // bitmask of entries not yet staged
    if (base + PA_K <= c1) {  // base is always 16B-aligned by construction
      int4 r4 = *reinterpret_cast<const int4*>(rows + base);
      int4 c4 = *reinterpret_cast<const int4*>(cols + base);
      int rr[PA_K] = {r4.x, r4.y, r4.z, r4.w};
      int cc[PA_K] = {c4.x, c4.y, c4.z, c4.w};
#pragma unroll
      for (int k = 0; k < PA_K; ++k) {
        bkt[2 * k] = rr[k] >> BSHIFT;
        packed[2 * k] =
            ((unsigned)(rr[k] & (BROWS - 1)) << 19) | (unsigned)cc[k];
        bkt[2 * k + 1] = cc[k] >> BSHIFT;
        packed[2 * k + 1] =
            ((unsigned)(cc[k] & (BROWS - 1)) << 19) | (unsigned)rr[k];
      }
      pend = (1u << (2 * PA_K)) - 1;
    } else {
#pragma unroll
      for (int k = 0; k < PA_K; ++k) {
        int e = base + k;
        if (e < c1) {
          int r = rows[e];
          int c = cols[e];
          bkt[2 * k] = r >> BSHIFT;
          packed[2 * k] = ((unsigned)(r & (BROWS - 1)) << 19) | (unsigned)c;
          bkt[2 * k + 1] = c >> BSHIFT;
          packed[2 * k + 1] = ((unsigned)(c & (BROWS - 1)) << 19) | (unsigned)r;
          pend |= 3u << (2 * k);
        }
      }
    }

    for (;;) {
#pragma unroll
      for (int k = 0; k < 2 * PA_K; ++k) {
        if (pend & (1u << k)) {
          int idx = atomicAdd(&scnt[bkt[k]], 1);
          if (idx < SCAP) {
            stage[bkt[k] * SPITCH + idx] = packed[k];
            pend &= ~(1u << k);
          } else {
            atomicAdd(&scnt[bkt[k]], -1);  // undo failed claim; retry after flush
          }
        }
      }
      __syncthreads();
      // flush ALL full 16-groups (one thread per bucket, conflict-free pitch)
      for (int bb = threadIdx.x; bb < nb; bb += PA_THREADS) {
        int cval = scnt[bb];
        if (cval >= 16) {
          while (cval >= 16) {
            int pos = atomicAdd(&gcur[bb], 16);
            unsigned v[16];
#pragma unroll
            for (int k = 0; k < 16; ++k) v[k] = stage[bb * SPITCH + k];
            uint4* dst = reinterpret_cast<uint4*>(&temp[pos]);
            dst[0] = make_uint4(v[0], v[1], v[2], v[3]);
            dst[1] = make_uint4(v[4], v[5], v[6], v[7]);
            dst[2] = make_uint4(v[8], v[9], v[10], v[11]);
            dst[3] = make_uint4(v[12], v[13], v[14], v[15]);
            for (int k = 0; k < cval - 16; ++k)
              stage[bb * SPITCH + k] = stage[bb * SPITCH + 16 + k];
            cval -= 16;
          }
          scnt[bb] = cval;
        }
      }
      int pend_total = __syncthreads_count(pend ? 1 : 0);
      if (pend_total == 0) break;
    }
  }
  // final drain: pad residue to a full aligned 16-group with sentinels
  __syncthreads();
  for (int bb = threadIdx.x; bb < nb; bb += PA_THREADS) {
    int cval = scnt[bb];
    if (cval > 0) {
      int pos = atomicAdd(&gcur[bb], 16);
      for (int k = 0; k < 16; ++k)
        temp[pos + k] = (k < cval) ? stage[bb * SPITCH + k] : SENTINEL;
    }
  }
}

// ---------------------------------------------------------------------------
// Per-bucket histogram: LDS atomics + coalesced contiguous cnt stores.
// ---------------------------------------------------------------------------
__global__ __launch_bounds__(512) void hist_bucket_kernel(
    const unsigned* __restrict__ temp, const int* __restrict__ gcur,
    int* __restrict__ cnt, int n) {
  __shared__ int lcnt[BROWS];
  int b = blockIdx.x;
  int base_row = b << BSHIFT;
  int nrows = min(BROWS, n - base_row);
  for (int r = threadIdx.x; r < BROWS; r += 512) lcnt[r] = 0;
  __syncthreads();
  int start = b * BCAP, end = gcur[b];
  for (int i = start + threadIdx.x; i < end; i += 512) {
    unsigned ent = temp[i];
    if (ent != SENTINEL) atomicAdd(&lcnt[ent >> 19], 1);
  }
  __syncthreads();
  for (int r = threadIdx.x; r < nrows; r += 512)
    cnt[base_row + r] = lcnt[r];
}

// phase1: per-block chunk reduction
__global__ __launch_bounds__(256) void scan_phase1(
    const int* __restrict__ cnt, int* __restrict__ block_sums, int n) {
  __shared__ int sdata[256];
  int base = blockIdx.x * SCAN_CHUNK;
  int sum = 0;
#pragma unroll
  for (int k = 0; k < 8; ++k) {
    int idx = base + k * 256 + threadIdx.x;
    if (idx < n) sum += cnt[idx];
  }
  sdata[threadIdx.x] = sum;
  __syncthreads();
  for (int s = 128; s > 0; s >>= 1) {
    if (threadIdx.x < s) sdata[threadIdx.x] += sdata[threadIdx.x + s];
    __syncthreads();
  }
  if (threadIdx.x == 0) block_sums[blockIdx.x] = sdata[0];
}

// phase2: single 256-wide exclusive scan over block sums; writes row_ptr[n]
__global__ __launch_bounds__(256) void scan_phase2(
    int* __restrict__ block_sums, int n_blocks, int* __restrict__ row_ptr, int n) {
  __shared__ int tmp[256];
  int v = (threadIdx.x < n_blocks) ? block_sums[threadIdx.x] : 0;
  tmp[threadIdx.x] = v;
  __syncthreads();
  for (int offs = 1; offs < 256; offs <<= 1) {
    int t = (threadIdx.x >= offs) ? tmp[threadIdx.x - offs] : 0;
    __syncthreads();
    tmp[threadIdx.x] += t;
    __syncthreads();
  }
  if (threadIdx.x < n_blocks) block_sums[threadIdx.x] = tmp[threadIdx.x] - v;
  if (threadIdx.x == 0) row_ptr[n] = tmp[255];
}

// phase3: per-block chunk scan with offset, writes row_ptr
__global__ __launch_bounds__(256) void scan_phase3(
    const int* __restrict__ cnt, const int* __restrict__ block_sums,
    int* __restrict__ row_ptr, int n) {
  __shared__ int tmp[256];
  __shared__ int s_carry;
  int base = blockIdx.x * SCAN_CHUNK;
  if (threadIdx.x == 0) s_carry = block_sums[blockIdx.x];
  __syncthreads();
#pragma unroll 1
  for (int k = 0; k < 8; ++k) {
    int idx = base + k * 256 + threadIdx.x;
    int v = (idx < n) ? cnt[idx] : 0;
    tmp[threadIdx.x] = v;
    __syncthreads();
    for (int offs = 1; offs < 256; offs <<= 1) {
      int t = (threadIdx.x >= offs) ? tmp[threadIdx.x - offs] : 0;
      __syncthreads();
      tmp[threadIdx.x] += t;
      __syncthreads();
    }
    int incl = tmp[threadIdx.x];
    int carry = s_carry;
    if (idx < n) row_ptr[idx] = carry + incl - v;
    __syncthreads();
    if (threadIdx.x == 0) s_carry = carry + tmp[255];
    __syncthreads();
  }
}

// rs = 1/sqrt(deg); rs2 = rs*rs (output scale); irs = sqrt(deg) (unscale)
__global__ __launch_bounds__(256) void rs_kernel(
    const int* __restrict__ cnt, float* __restrict__ rs,
    float* __restrict__ rs2, float* __restrict__ irs, int n) {
  int i = blockIdx.x * blockDim.x + threadIdx.x;
  if (i < n) {
    float d = (float)cnt[i];
    float r = (d > 0.0f) ? 1.0f / sqrtf(d) : 1.0f;
    rs[i] = r;
    rs2[i] = r * r;
    irs[i] = (d > 0.0f) ? sqrtf(d) : 1.0f;
  }
}

// gcur init for fixed-capacity buckets
__global__ __launch_bounds__(256) void bucket_init_kernel(
    int* __restrict__ gcur, int nb) {
  int b = blockIdx.x * blockDim.x + threadIdx.x;
  if (b < nb) gcur[b] = b * BCAP;
}

// ---------------------------------------------------------------------------
// Pass B: per bucket, scatter bucket entries to exact CSR positions.
// ---------------------------------------------------------------------------
__global__ __launch_bounds__(PB_THREADS) void pass_b_kernel(
    const unsigned* __restrict__ temp, const int* __restrict__ gcur,
    const int* __restrict__ row_ptr, int* __restrict__ csr_col, int nb, int n) {
  __shared__ int ldscur[BROWS];
  for (int b = blockIdx.x; b < nb; b += gridDim.x) {
    int base_row = b << BSHIFT;
    int nrows = min(BROWS, n - base_row);
    for (int r = threadIdx.x; r < nrows; r += PB_THREADS)
      ldscur[r] = row_ptr[base_row + r];
    __syncthreads();
    int start = b * BCAP, end = gcur[b];
    for (int i = start + threadIdx.x; i < end; i += PB_THREADS) {
      unsigned ent = temp[i];
      if (ent != SENTINEL) {
        int col = (int)(ent & 0x7FFFFu);
        int rlow = (int)(ent >> 19);
        int p = atomicAdd(&ldscur[rlow], 1);
        csr_col[p] = col;
      }
    }
    __syncthreads();
  }
}

// ---------------------------------------------------------------------------
// SpMM in S-space, fp8 storage: one wave per row; 4 lanes per row x 16B
// (uint4 = 16 fp8) -> one gather instruction moves 16 rows x 64B = 1KB and
// each row is exactly ONE cache line. Main loop: 32 edges/iter unmasked,
// 2 gathers in flight; tail: one masked 32-edge pass (clamped dup line,
// dwords zeroed -- fp8 0x00 decodes to +0). acc fp32; epilogue rs2[row],
// hardware cvt_pk encode; lanes q==0 store the 64B row.
// ---------------------------------------------------------------------------
__global__ __launch_bounds__(256) void spmm_kernel(
    const int* __restrict__ row_ptr, const int* __restrict__ csr_col,
    const float* __restrict__ rs2, const uint4* __restrict__ cur4,
    uint4* __restrict__ next4, int n_rows) {
  int row  = blockIdx.x * (blockDim.x >> 6) + (threadIdx.x >> 6);
  int lane = threadIdx.x & 63;
  int q    = lane >> 2;   // which edge of the group of 16
  int sub  = lane & 3;    // 16B chunk (16 fp8 dims) within the 64B row
  if (row >= n_rows) return;
  int start = row_ptr[row];
  int end   = row_ptr[row + 1];
  float acc[16];
#pragma unroll
  for (int d = 0; d < 16; ++d) acc[d] = 0.0f;
  int e = start;
  for (; e + 32 <= end; e += 32) {  // unmasked main loop
    int c0 = ld_nt_int(csr_col + e + q);
    int c1 = ld_nt_int(csr_col + e + 16 + q);
    uint4 g0 = cur4[(size_t)c0 * 4 + sub];
    uint4 g1 = cur4[(size_t)c1 * 4 + sub];
    ACC_DW(g0.x, 0); ACC_DW(g0.y, 4); ACC_DW(g0.z, 8); ACC_DW(g0.w, 12);
    ACC_DW(g1.x, 0); ACC_DW(g1.y, 4); ACC_DW(g1.z, 8); ACC_DW(g1.w, 12);
  }
  if (e < end) {  // single masked tail pass (1..31 edges)
    int i0 = e + q, i1 = e + 16 + q;
    bool m0 = i0 < end, m1 = i1 < end;
    int c0 = ld_nt_int(csr_col + (m0 ? i0 : end - 1));
    int c1 = ld_nt_int(csr_col + (m1 ? i1 : end - 1));
    uint4 g0 = cur4[(size_t)c0 * 4 + sub];
    uint4 g1 = cur4[(size_t)c1 * 4 + sub];
    if (!m0) g0 = make_uint4(0, 0, 0, 0);
    if (!m1) g1 = make_uint4(0, 0, 0, 0);
    ACC_DW(g0.x, 0); ACC_DW(g0.y, 4); ACC_DW(g0.z, 8); ACC_DW(g0.w, 12);
    ACC_DW(g1.x, 0); ACC_DW(g1.y, 4); ACC_DW(g1.z, 8); ACC_DW(g1.w, 12);
  }
  // combine the sixteen group partial sums (over q; sub stays fixed)
#pragma unroll
  for (int offs = 4; offs <= 32; offs <<= 1) {
#pragma unroll
    for (int d = 0; d < 16; ++d) acc[d] += __shfl_xor(acc[d], offs, 64);
  }
  if (q == 0) {
    float s = rs2[row];  // FP8_SCALE propagates: out = rs2 * sum(scaled in)
    int w0 = 0, w1 = 0, w2 = 0, w3 = 0;
    w0 = __builtin_amdgcn_cvt_pk_fp8_f32(acc[0] * s, acc[1] * s, w0, false);
    w0 = __builtin_amdgcn_cvt_pk_fp8_f32(acc[2] * s, acc[3] * s, w0, true);
    w1 = __builtin_amdgcn_cvt_pk_fp8_f32(acc[4] * s, acc[5] * s, w1, false);
    w1 = __builtin_amdgcn_cvt_pk_fp8_f32(acc[6] * s, acc[7] * s, w1, true);
    w2 = __builtin_amdgcn_cvt_pk_fp8_f32(acc[8] * s, acc[9] * s, w2, false);
    w2 = __builtin_amdgcn_cvt_pk_fp8_f32(acc[10] * s, acc[11] * s, w2, true);
    w3 = __builtin_amdgcn_cvt_pk_fp8_f32(acc[12] * s, acc[13] * s, w3, false);
    w3 = __builtin_amdgcn_cvt_pk_fp8_f32(acc[14] * s, acc[15] * s, w3, true);
    next4[(size_t)row * 4 + sub] =
        make_uint4((unsigned)w0, (unsigned)w1, (unsigned)w2, (unsigned)w3);
  }
}

// ---------------------------------------------------------------------------
// Layer-3 batch-restricted SpMM: only the 2*batch rows needed by the output.
// acc[b] += rs[row]/FP8_SCALE * sum_{c in N(row)} S2fp8[c]
// One wave per (batch-slot, side); 8 lanes x 8B per row, masked 2-deep loop.
// ---------------------------------------------------------------------------
__global__ __launch_bounds__(256) void batch_spmm_kernel(
    const int* __restrict__ u, const int* __restrict__ it,
    const int* __restrict__ row_ptr, const int* __restrict__ csr_col,
    const float* __restrict__ rs, const uint2* __restrict__ cur2,
    float* __restrict__ accU, float* __restrict__ accI, int batch, int nU) {
  int t    = blockIdx.x * (blockDim.x >> 6) + (threadIdx.x >> 6);
  int lane = threadIdx.x & 63;
  int q    = lane >> 3;  // which edge of the group of 8
  int sub  = lane & 7;   // 8B chunk (8 fp8 dims) within the 64B row
  if (t >= 2 * batch) return;
  int b = t >> 1;
  bool uside = (t & 1) == 0;
  int row = uside ? u[b] : (it[b] + nU);
  int start = row_ptr[row];
  int end   = row_ptr[row + 1];
  float acc[8];
#pragma unroll
  for (int d = 0; d < 8; ++d) acc[d] = 0.0f;
  for (int e = start; e < end; e += 16) {
    int i0 = e + q, i1 = e + 8 + q;
    bool m0 = i0 < end, m1 = i1 < end;
    int c0 = ld_nt_int(csr_col + (m0 ? i0 : end - 1));
    int c1 = ld_nt_int(csr_col + (m1 ? i1 : end - 1));
    uint2 g0 = cur2[(size_t)c0 * 8 + sub];
    uint2 g1 = cur2[(size_t)c1 * 8 + sub];
    if (!m0) g0 = make_uint2(0, 0);
    if (!m1) g1 = make_uint2(0, 0);
    ACC_DW(g0.x, 0); ACC_DW(g0.y, 4);
    ACC_DW(g1.x, 0); ACC_DW(g1.y, 4);
  }
#pragma unroll
  for (int offs = 8; offs <= 32; offs <<= 1) {
#pragma unroll
    for (int d = 0; d < 8; ++d) acc[d] += __shfl_xor(acc[d], offs, 64);
  }
  if (q == 0) {
    float s = rs[row] * FP8_INV;
    float* dst = (uside ? accU : accI) + (size_t)b * DIMS + sub * 8;
    float4 o0 = *reinterpret_cast<float4*>(dst);
    float4 o1 = *reinterpret_cast<float4*>(dst + 4);
    o0.x += acc[0] * s; o0.y += acc[1] * s;
    o0.z += acc[2] * s; o0.w += acc[3] * s;
    o1.x += acc[4] * s; o1.y += acc[5] * s;
    o1.z += acc[6] * s; o1.w += acc[7] * s;
    *reinterpret_cast<float4*>(dst) = o0;
    *reinterpret_cast<float4*>(dst + 4) = o1;
  }
}

// ---------------------------------------------------------------------------
// Layer-0 batch gather: exact fp32 E0 rows straight from U/V (initializes acc)
// ---------------------------------------------------------------------------
__global__ __launch_bounds__(256) void gather0_kernel(
    const int* __restrict__ u, const int* __restrict__ it,
    const float* __restrict__ U, const float* __restrict__ V,
    float* __restrict__ accU, float* __restrict__ accI, int batch) {
  int b    = blockIdx.x * (blockDim.x >> 6) + (threadIdx.x >> 6);
  int lane = threadIdx.x & 63;
  if (b >= batch) return;
  accU[b * DIMS + lane] = U[u[b] * DIMS + lane];
  accI[b * DIMS + lane] = V[it[b] * DIMS + lane];
}

// Layer-k batch gather from S-space fp8: unscale by irs/FP8_SCALE
__global__ __launch_bounds__(256) void gather_s_kernel(
    const int* __restrict__ u, const int* __restrict__ it,
    const unsigned char* __restrict__ curS, const float* __restrict__ irs,
    float* __restrict__ accU, float* __restrict__ accI, int batch, int nU) {
  int b    = blockIdx.x * (blockDim.x >> 6) + (threadIdx.x >> 6);
  int lane = threadIdx.x & 63;
  if (b >= batch) return;
  int ru = u[b];
  int ri = it[b] + nU;
  int bu = (int)curS[(size_t)ru * DIMS + lane];
  int bi = (int)curS[(size_t)ri * DIMS + lane];
  v2f du = __builtin_amdgcn_cvt_pk_f32_fp8(bu, false);
  v2f di = __builtin_amdgcn_cvt_pk_f32_fp8(bi, false);
  accU[b * DIMS + lane] += du[0] * (irs[ru] * FP8_INV);
  accI[b * DIMS + lane] += di[0] * (irs[ri] * FP8_INV);
}

__global__ __launch_bounds__(256) void score_kernel(
    const float* __restrict__ accU, const float* __restrict__ accI,
    float* __restrict__ out, int batch) {
  int b    = blockIdx.x * (blockDim.x >> 6) + (threadIdx.x >> 6);
  int lane = threadIdx.x & 63;
  if (b >= batch) return;
  float v = accU[b * DIMS + lane] * accI[b * DIMS + lane];
  for (int offs = 32; offs > 0; offs >>= 1) v += __shfl_down(v, offs, 64);
  if (lane == 0) out[b] = v * (1.0f / 16.0f);
}

// ---------------------------------------------------------------------------
extern "C" void kernel_launch(void* const* d_in, const int* in_sizes, int n_in,
                              void* d_out, int out_size, void* d_ws, size_t ws_size,
                              hipStream_t stream) {
  const int*   u     = (const int*)d_in[0];
  const int*   it    = (const int*)d_in[1];
  const int*   arows = (const int*)d_in[2];
  const int*   acols = (const int*)d_in[3];
  const float* U     = (const float*)d_in[5];
  const float* V     = (const float*)d_in[6];

  const int batch = in_sizes[0];
  const int nnz   = in_sizes[2];
  const int nU    = in_sizes[5] / DIMS;
  const int nV    = in_sizes[6] / DIMS;
  const int N     = nU + nV;
  const int n_scan_blocks = (N + SCAN_CHUNK - 1) / SCAN_CHUNK;
  const int NB    = (N + BROWS - 1) >> BSHIFT;  // 293
  const size_t esbytes = (size_t)N * DIMS;      // fp8 embeddings (19.2 MB)
  const size_t tbytes  = (size_t)NB * BCAP * 4;
  const size_t xbytes  = tbytes > esbytes ? tbytes : esbytes;

  // pass_a grid: each block covers PA_CHUNK first-half edge-pairs (mirrored)
  const int half  = nnz >> 1;
  const int PA_B  = (half + PA_CHUNK - 1) / PA_CHUNK;

  char*  ws  = (char*)d_ws;
  size_t off = 0;
  auto take = [&](size_t bytes) -> void* {
    void* p = ws + off;
    off = (off + bytes + 255) & ~(size_t)255;
    return p;
  };
  int*     cnt        = (int*)take((size_t)N * 4);
  float*   rs         = (float*)take((size_t)N * 4);
  float*   rs2        = (float*)take((size_t)N * 4);
  float*   irs        = (float*)take((size_t)N * 4);
  int*     row_ptr    = (int*)take((size_t)(N + 1) * 4);
  int*     block_sums = (int*)take((size_t)256 * 4);
  int*     gcur       = (int*)take((size_t)NB * 4);
  int*     csr_col    = (int*)take((size_t)nnz * 4);
  char*    X          = (char*)take(xbytes);   // temp (build), then bufA (Es)
  unsigned char* bufB = (unsigned char*)take(esbytes);
  float*   accU       = (float*)take((size_t)batch * DIMS * 4);
  float*   accI       = (float*)take((size_t)batch * DIMS * 4);
  unsigned* temp      = (unsigned*)X;
  unsigned char* bufA = (unsigned char*)X;

  // ---- CSR build (uses X as temp) ----
  bucket_init_kernel<<<(NB + 255) / 256, 256, 0, stream>>>(gcur, NB);
  pass_a_kernel<<<PA_B, PA_THREADS, 0, stream>>>(arows, acols, temp, gcur, nnz, NB);
  hist_bucket_kernel<<<NB, 512, 0, stream>>>(temp, gcur, cnt, N);
  scan_phase1<<<n_scan_blocks, 256, 0, stream>>>(cnt, block_sums, N);
  scan_phase2<<<1, 256, 0, stream>>>(block_sums, n_scan_blocks, row_ptr, N);
  scan_phase3<<<n_scan_blocks, 256, 0, stream>>>(cnt, block_sums, row_ptr, N);
  rs_kernel<<<(N + 255) / 256, 256, 0, stream>>>(cnt, rs, rs2, irs, N);
  pass_b_kernel<<<NB, PB_THREADS, 0, stream>>>(temp, gcur, row_ptr,
                                               csr_col, NB, N);

  // ---- batch acc init with exact fp32 E0 rows (no memset needed) ----
  gather0_kernel<<<(batch + 3) / 4, 256, 0, stream>>>(u, it, U, V, accU, accI,
                                                      batch);

  // ---- Es0 = FP8_SCALE*rs*E0 in fp8 (X becomes bufA; temp is dead) ----
  {
    int total = N * DIMS;
    int t4 = total / 4;
    init_es_kernel<<<(t4 + 255) / 256, 256, 0, stream>>>(
        U, V, rs, (unsigned*)bufA, nU * DIMS, total);
  }

  // ---- layers 1,2: full SpMM + batch gather; layer 3: batch-restricted ----
  unsigned char* cur = bufA;
  unsigned char* nxt = bufB;
  for (int layer = 0; layer < 2; ++layer) {
    spmm_kernel<<<(N + 3) / 4, 256, 0, stream>>>(
        row_ptr, csr_col, rs2, (const uint4*)cur, (uint4*)nxt, N);
    gather_s_kernel<<<(batch + 3) / 4, 256, 0, stream>>>(u, it, nxt, irs, accU,
                                                         accI, batch, nU);
    unsigned char* t = cur; cur = nxt; nxt = t;
  }
  batch_spmm_kernel<<<(2 * batch + 3) / 4, 256, 0, stream>>>(
      u, it, row_ptr, csr_col, rs, (const uint2*)cur, accU, accI, batch, nU);

  score_kernel<<<(batch + 3) / 4, 256, 0, stream>>>(accU, accI, (float*)d_out, batch);
}